// Round 1
// 254.098 us; speedup vs baseline: 1.2854x; 1.2854x over previous
//
#include <hip/hip_runtime.h>
#include <hip/hip_bf16.h>
#include <math.h>

#define HDIM 1024
#define SEQ  2048
#define BATCH 2
#define NHEAD 16
#define HEADD 64

typedef short bf16x8 __attribute__((ext_vector_type(8)));
typedef float f32x4  __attribute__((ext_vector_type(4)));
typedef unsigned short u16x8 __attribute__((ext_vector_type(8)));

__device__ __forceinline__ unsigned short f2bf(float f) {
    unsigned u = __float_as_uint(f);
    unsigned r = (u + 0x7FFFu + ((u >> 16) & 1u)) >> 16;
    return (unsigned short)r;
}
__device__ __forceinline__ float b2f(unsigned short s) {
    return __uint_as_float(((unsigned)s) << 16);
}
__device__ __forceinline__ unsigned pk2bf(float lo, float hi) {
    __hip_bfloat162 h = __float22bfloat162_rn(float2{lo, hi});
    unsigned r;
    __builtin_memcpy(&r, &h, 4);
    return r;
}
__device__ __forceinline__ float fexp2(float x) {
#if __has_builtin(__builtin_amdgcn_exp2f)
    return __builtin_amdgcn_exp2f(x);
#else
    return exp2f(x);
#endif
}
__device__ __forceinline__ void gld16(void* lds, const void* g) {
    __builtin_amdgcn_global_load_lds(
        (const __attribute__((address_space(1))) unsigned int*)(g),
        (__attribute__((address_space(3))) unsigned int*)(lds),
        16, 0, 0);
}

// swizzled element offset for row-major [*][64] bf16 tiles (128B rows, 8 chunks of 16B)
#define SWZ(row, chunk) (((row) * 64) + (((chunk) ^ ((row) & 7)) << 3))

// ---------------- LayerNorm: fp32 in, bf16 out ----------------
__global__ __launch_bounds__(256) void ln_kernel(const float* __restrict__ x,
                                                 const float* __restrict__ gw,
                                                 const float* __restrict__ bw,
                                                 unsigned short* __restrict__ y)
{
    int row = blockIdx.x;
    int t = threadIdx.x;
    const float* xr = x + (size_t)row * HDIM;
    float4 v = *(const float4*)(xr + t * 4);
    float s1 = v.x + v.y + v.z + v.w;
    float s2 = v.x * v.x + v.y * v.y + v.z * v.z + v.w * v.w;
#pragma unroll
    for (int m = 1; m < 64; m <<= 1) {
        s1 += __shfl_xor(s1, m);
        s2 += __shfl_xor(s2, m);
    }
    __shared__ float red[8];
    int wid = t >> 6;
    if ((t & 63) == 0) { red[wid * 2] = s1; red[wid * 2 + 1] = s2; }
    __syncthreads();
    if (t == 0) {
        float a = red[0] + red[2] + red[4] + red[6];
        float b = red[1] + red[3] + red[5] + red[7];
        red[0] = a; red[1] = b;
    }
    __syncthreads();
    float mu  = red[0] * (1.0f / HDIM);
    float var = red[1] * (1.0f / HDIM) - mu * mu;
    float rs  = rsqrtf(var + 1e-5f);
    float4 g4 = *(const float4*)(gw + t * 4);
    float4 b4 = *(const float4*)(bw + t * 4);
    ushort4 o;
    o.x = f2bf((v.x - mu) * rs * g4.x + b4.x);
    o.y = f2bf((v.y - mu) * rs * g4.y + b4.y);
    o.z = f2bf((v.z - mu) * rs * g4.z + b4.z);
    o.w = f2bf((v.w - mu) * rs * g4.w + b4.w);
    *(ushort4*)(y + (size_t)row * HDIM + t * 4) = o;
}

// ------------- weight fp32 [K][N] -> bf16 transposed [N][K] -------------
__global__ __launch_bounds__(256) void wconv_kernel(const float* __restrict__ W,
                                                    unsigned short* __restrict__ WT,
                                                    int K, int N)
{
    __shared__ float tile[32][33];
    int n0 = blockIdx.x * 32, k0 = blockIdx.y * 32;
    int t = threadIdx.x, c = t & 31, r = t >> 5;
#pragma unroll
    for (int i = 0; i < 4; ++i)
        tile[r + 8 * i][c] = W[(size_t)(k0 + r + 8 * i) * N + n0 + c];
    __syncthreads();
#pragma unroll
    for (int i = 0; i < 4; ++i)
        WT[(size_t)(n0 + r + 8 * i) * K + k0 + c] = f2bf(tile[c][r + 8 * i]);
}

// ------------- MFMA GEMM: C[M,N] = A[M,K] @ BT[N,K]^T + bias (+EPI) -------------
// 128x128 tile, BK=64, double-buffered LDS (2x32KB), prefetch-before-compute,
// one barrier per K-tile.  LDS tiles XOR-swizzled via pre-swizzled global source
// (linear global_load_lds dest) + swizzled ds_read -- rule-21 pattern.
template <int EPI>
__global__ __launch_bounds__(256, 2) void mgemm(const unsigned short* __restrict__ A,
                                                const unsigned short* __restrict__ BT,
                                                const float* __restrict__ bias,
                                                const float* __restrict__ resid,
                                                float* __restrict__ Cf,
                                                unsigned short* __restrict__ Cb,
                                                int M, int N, int K)
{
    __shared__ char smem[65536];   // [2 bufs][A 16KB | B 16KB]
    int t = threadIdx.x;
    int bn = blockIdx.x * 128, bm = blockIdx.y * 128;
    int l = t & 63, w = t >> 6;
    int wm = w >> 1, wn = w & 1;
    int lrow = l & 15, kq = l >> 4;   // kq: 16B chunk within the 32-elem k-half

    f32x4 acc[4][4];
#pragma unroll
    for (int i = 0; i < 4; ++i)
#pragma unroll
        for (int j = 0; j < 4; ++j) acc[i][j] = {0.f, 0.f, 0.f, 0.f};

    // staging geometry: tile = 128 rows x 8 chunks(16B) per operand = 1024 chunks;
    // 256 threads -> 4 chunks/thread.  LDS dest linear (chunk cid at cid*16 bytes,
    // wave-uniform base + lane*16); global source column pre-swizzled c^(row&7).
    const unsigned short* Ap[4];
    const unsigned short* Bp[4];
    int ld[4];
#pragma unroll
    for (int i = 0; i < 4; ++i) {
        int cid = i * 256 + t;
        int row = cid >> 3, c = cid & 7;
        int gc = (c ^ (row & 7)) << 3;
        Ap[i] = A + (size_t)(bm + row) * K + gc;
        Bp[i] = BT + (size_t)(bn + row) * K + gc;
        ld[i] = cid << 4;
    }

    int nt = K >> 6;
    // prologue: stage K-tile 0 into buf0
#pragma unroll
    for (int i = 0; i < 4; ++i) {
        gld16(smem + ld[i], Ap[i]);
        gld16(smem + 16384 + ld[i], Bp[i]);
    }
    __syncthreads();   // vmcnt(0) drain + barrier: tile 0 ready

    for (int tk = 0; tk < nt; ++tk) {
        int cur = (tk & 1) << 15;
        if (tk + 1 < nt) {
            // issue next-tile prefetch BEFORE compute; drained by the barrier
            // at the END of this iteration -> latency hidden under 32 MFMAs.
            int k0 = (tk + 1) << 6;
            int nxt = 32768 - cur;
#pragma unroll
            for (int i = 0; i < 4; ++i) {
                gld16(smem + nxt + ld[i], Ap[i] + k0);
                gld16(smem + nxt + 16384 + ld[i], Bp[i] + k0);
            }
        }
        const unsigned short* sA = (const unsigned short*)(smem + cur);
        const unsigned short* sB = (const unsigned short*)(smem + cur + 16384);
#pragma unroll
        for (int kk = 0; kk < 2; ++kk) {
            bf16x8 af[4], bv[4];
#pragma unroll
            for (int mi = 0; mi < 4; ++mi)
                af[mi] = *(const bf16x8*)(sA + SWZ(wm * 64 + mi * 16 + lrow, kk * 4 + kq));
#pragma unroll
            for (int ni = 0; ni < 4; ++ni)
                bv[ni] = *(const bf16x8*)(sB + SWZ(wn * 64 + ni * 16 + lrow, kk * 4 + kq));
#pragma unroll
            for (int mi = 0; mi < 4; ++mi)
#pragma unroll
                for (int ni = 0; ni < 4; ++ni)
                    acc[mi][ni] = __builtin_amdgcn_mfma_f32_16x16x32_bf16(af[mi], bv[ni], acc[mi][ni], 0, 0, 0);
        }
        __syncthreads();   // drains prefetch vmcnt + flips buffers
    }

    int crow = (l >> 4) * 4;
    int ccol = l & 15;
#pragma unroll
    for (int mi = 0; mi < 4; ++mi) {
#pragma unroll
        for (int ni = 0; ni < 4; ++ni) {
            int gcol = bn + wn * 64 + ni * 16 + ccol;
            float bv = bias[gcol];
#pragma unroll
            for (int r = 0; r < 4; ++r) {
                int grow = bm + wm * 64 + mi * 16 + crow + r;
                size_t off = (size_t)grow * N + gcol;
                float v = acc[mi][ni][r] + bv;
                if (EPI == 1) {
                    Cf[off] = v + resid[off];
                } else if (EPI == 2) {
                    v = 0.5f * v * (1.0f + erff(v * 0.70710678118654752f));
                    Cb[off] = f2bf(v);
                } else {
                    Cb[off] = f2bf(v);
                }
            }
        }
    }
}

// ---------------- MFMA flash attention (swapped QK^T, lane-local softmax) ----------------
// block = (q-tile of 64, head, batch); 4 waves, wave w owns q rows [16w,16w+16)
__global__ __launch_bounds__(256) void mattn(const unsigned short* __restrict__ qkv,
                                             unsigned short* __restrict__ out)
{
    __shared__ unsigned short Qs[64 * 64];     // [q][d] swizzled
    __shared__ unsigned short Ks[64 * 64];     // [k][d] swizzled
    __shared__ unsigned short Vt[64 * 64];     // [d][k] swizzled (transposed V)
    __shared__ unsigned short Ps[4 * 16 * 64]; // per-wave [q16][k64] swizzled
    int t = threadIdx.x;
    int w = t >> 6, l = t & 63;
    int lr = l & 15, lh = l >> 4;
    int q0 = blockIdx.x * 64;
    int hh = blockIdx.y, b = blockIdx.z;
    const unsigned short* Qg = qkv + (size_t)b * SEQ * 3072 + hh * 64;
    const unsigned short* Kg = Qg + 1024;
    const unsigned short* Vg = Qg + 2048;

    // ---- stage Q (pre-swizzled global source) ----
#pragma unroll
    for (int i = 0; i < 2; ++i) {
        int chunkid = (w * 2 + i) * 64 + l;
        int row = chunkid >> 3, c = chunkid & 7;
        gld16(((char*)Qs) + chunkid * 16,
              Qg + (size_t)(q0 + row) * 3072 + ((c ^ (row & 7)) << 3));
    }
    __syncthreads();
    bf16x8 qa[2];
#pragma unroll
    for (int ks = 0; ks < 2; ++ks)
        qa[ks] = *(const bf16x8*)(Qs + SWZ(w * 16 + lr, ks * 4 + lh));

    f32x4 o[4];
#pragma unroll
    for (int i = 0; i < 4; ++i) o[i] = {0.f, 0.f, 0.f, 0.f};
    float mr = -3.0e38f, lsum = 0.f;   // per-lane: q-row = w*16 + lr
    unsigned short* Pw = Ps + w * (16 * 64);
    const float C = 0.18033688011112042f;  // 0.125 * log2(e)

    // hoisted staging pointers (advance by 64 rows per tile)
    int ck0 = (w * 2) * 64 + l, ck1 = (w * 2 + 1) * 64 + l;
    int kr0 = ck0 >> 3, kc0 = ck0 & 7;
    int kr1 = ck1 >> 3, kc1 = ck1 & 7;
    const unsigned short* Kp0 = Kg + (size_t)kr0 * 3072 + ((kc0 ^ (kr0 & 7)) << 3);
    const unsigned short* Kp1 = Kg + (size_t)kr1 * 3072 + ((kc1 ^ (kr1 & 7)) << 3);
    char* Kd0 = (char*)Ks + ck0 * 16;
    char* Kd1 = (char*)Ks + ck1 * 16;
    int vk = (t & 31) * 2;
    int vd0 = ((t >> 5) & 7) * 8;
    const unsigned short* Vp0 = Vg + (size_t)vk * 3072 + vd0;
    const unsigned short* Vp1 = Vp0 + 3072;

    for (int kv = 0; kv < SEQ; kv += 64) {
        __syncthreads();  // all waves done reading prev K/V
        gld16(Kd0, Kp0);
        gld16(Kd1, Kp1);
        u16x8 v0 = *(const u16x8*)Vp0;
        u16x8 v1 = *(const u16x8*)Vp1;
        Kp0 += 64 * 3072; Kp1 += 64 * 3072;
        Vp0 += 64 * 3072; Vp1 += 64 * 3072;
#pragma unroll
        for (int j = 0; j < 8; ++j) {
            int d = vd0 + j;
            unsigned pack = (unsigned)(unsigned short)v0[j] | ((unsigned)(unsigned short)v1[j] << 16);
            *(unsigned*)(Vt + SWZ(d, vk >> 3) + (vk & 7)) = pack;
        }
        __syncthreads();  // K/V staged

        // swapped QK^T: S^T = K·Q^T -> lane holds q=lr, k=ni*16+lh*4+r (raw scores)
        f32x4 s[4];
#pragma unroll
        for (int ni = 0; ni < 4; ++ni) s[ni] = {0.f, 0.f, 0.f, 0.f};
#pragma unroll
        for (int ks = 0; ks < 2; ++ks) {
#pragma unroll
            for (int ni = 0; ni < 4; ++ni) {
                bf16x8 kb = *(const bf16x8*)(Ks + SWZ(ni * 16 + lr, ks * 4 + lh));
                s[ni] = __builtin_amdgcn_mfma_f32_16x16x32_bf16(kb, qa[ks], s[ni], 0, 0, 0);
            }
        }
        // row max: 15 in-reg + 2 shfl (lanes sharing lr)
        float mx = s[0][0];
#pragma unroll
        for (int ni = 0; ni < 4; ++ni)
#pragma unroll
            for (int r = 0; r < 4; ++r) mx = fmaxf(mx, s[ni][r]);
        mx = fmaxf(mx, __shfl_xor(mx, 16));
        mx = fmaxf(mx, __shfl_xor(mx, 32));
        // defer-max: only rescale when growth beyond e^8 bound (always on tile 0)
        if (__any(mx > mr + 64.0f)) {
            float mn = fmaxf(mr, mx);
            float corr = fexp2((mr - mn) * C);
            mr = mn;
            lsum *= corr;
            float cr[4];
#pragma unroll
            for (int r = 0; r < 4; ++r) cr[r] = __shfl(corr, lh * 4 + r, 16);
#pragma unroll
            for (int nd = 0; nd < 4; ++nd) {
                o[nd][0] *= cr[0]; o[nd][1] *= cr[1];
                o[nd][2] *= cr[2]; o[nd][3] *= cr[3];
            }
        }
        float mc = mr * C;
        float rsum = 0.f;
#pragma unroll
        for (int ni = 0; ni < 4; ++ni)
#pragma unroll
            for (int r = 0; r < 4; ++r) {
                float p = fexp2(fmaf(s[ni][r], C, -mc));
                s[ni][r] = p;
                rsum += p;
            }
        rsum += __shfl_xor(rsum, 16);
        rsum += __shfl_xor(rsum, 32);
        lsum += rsum;
        // P write: packed pairs (adjacent k = r, r+1)
#pragma unroll
        for (int ni = 0; ni < 4; ++ni)
#pragma unroll
            for (int rp = 0; rp < 2; ++rp) {
                int k = ni * 16 + lh * 4 + rp * 2;
                *(unsigned*)(Pw + SWZ(lr, k >> 3) + (k & 7)) =
                    pk2bf(s[ni][rp * 2], s[ni][rp * 2 + 1]);
            }
        // PV: O[q16][d64] += P[q16][k64] @ V[k64][d64]
#pragma unroll
        for (int ks = 0; ks < 2; ++ks) {
            bf16x8 pa = *(const bf16x8*)(Pw + SWZ(lr, ks * 4 + lh));
#pragma unroll
            for (int nd = 0; nd < 4; ++nd) {
                bf16x8 vb = *(const bf16x8*)(Vt + SWZ(nd * 16 + lr, ks * 4 + lh));
                o[nd] = __builtin_amdgcn_mfma_f32_16x16x32_bf16(pa, vb, o[nd], 0, 0, 0);
            }
        }
    }
    // epilogue: redistribute 1/lsum to PV row owners
    float inv = 1.0f / lsum;
    float ir[4];
#pragma unroll
    for (int r = 0; r < 4; ++r) ir[r] = __shfl(inv, lh * 4 + r, 16);
#pragma unroll
    for (int r = 0; r < 4; ++r) {
        int q = q0 + w * 16 + lh * 4 + r;
#pragma unroll
        for (int nd = 0; nd < 4; ++nd) {
            int d = nd * 16 + lr;
            out[(size_t)((size_t)b * SEQ + q) * HDIM + hh * 64 + d] = f2bf(o[nd][r] * ir[r]);
        }
    }
}

extern "C" void kernel_launch(void* const* d_in, const int* in_sizes, int n_in,
                              void* d_out, int out_size, void* d_ws, size_t ws_size,
                              hipStream_t stream)
{
    const float* x     = (const float*)d_in[0];
    const float* ln1_g = (const float*)d_in[1];
    const float* ln1_b = (const float*)d_in[2];
    const float* W_qkv = (const float*)d_in[3];
    const float* b_qkv = (const float*)d_in[4];
    const float* W_out = (const float*)d_in[5];
    const float* b_out = (const float*)d_in[6];
    const float* ln2_g = (const float*)d_in[7];
    const float* ln2_b = (const float*)d_in[8];
    const float* W1    = (const float*)d_in[9];
    const float* b1    = (const float*)d_in[10];
    const float* W2    = (const float*)d_in[11];
    const float* b2    = (const float*)d_in[12];
    float* out = (float*)d_out;
    char* ws8  = (char*)d_ws;

    const int M = BATCH * SEQ;  // 4096
    const size_t MB = 1048576;

    unsigned short* hbuf = (unsigned short*)(ws8);
    unsigned short* qkvb = (unsigned short*)(ws8 + 8 * MB);
    unsigned short* attb = (unsigned short*)(ws8 + 32 * MB);
    unsigned short* ffn1 = (unsigned short*)(ws8 + 8 * MB);
    unsigned short* WqT  = (unsigned short*)(ws8 + 40 * MB);
    unsigned short* WoT  = (unsigned short*)(ws8 + 46 * MB);
    unsigned short* W1T  = (unsigned short*)(ws8 + 48 * MB);
    unsigned short* W2T  = (unsigned short*)(ws8 + 56 * MB);

    wconv_kernel<<<dim3(3 * HDIM / 32, HDIM / 32), 256, 0, stream>>>(W_qkv, WqT, HDIM, 3 * HDIM);
    wconv_kernel<<<dim3(HDIM / 32, HDIM / 32), 256, 0, stream>>>(W_out, WoT, HDIM, HDIM);
    wconv_kernel<<<dim3(4 * HDIM / 32, HDIM / 32), 256, 0, stream>>>(W1, W1T, HDIM, 4 * HDIM);
    wconv_kernel<<<dim3(HDIM / 32, 4 * HDIM / 32), 256, 0, stream>>>(W2, W2T, 4 * HDIM, HDIM);

    ln_kernel<<<M, 256, 0, stream>>>(x, ln1_g, ln1_b, hbuf);
    mgemm<0><<<dim3(3 * HDIM / 128, M / 128), 256, 0, stream>>>(hbuf, WqT, b_qkv, nullptr, nullptr, qkvb, M, 3 * HDIM, HDIM);
    mattn<<<dim3(SEQ / 64, NHEAD, BATCH), 256, 0, stream>>>(qkvb, attb);
    mgemm<1><<<dim3(HDIM / 128, M / 128), 256, 0, stream>>>(attb, WoT, b_out, x, out, nullptr, M, HDIM, HDIM);
    ln_kernel<<<M, 256, 0, stream>>>(out, ln2_g, ln2_b, hbuf);
    mgemm<2><<<dim3(4 * HDIM / 128, M / 128), 256, 0, stream>>>(hbuf, W1T, b1, nullptr, nullptr, ffn1, M, 4 * HDIM, HDIM);
    mgemm<1><<<dim3(HDIM / 128, M / 128), 256, 0, stream>>>(ffn1, W2T, b2, out, out, nullptr, M, HDIM, 4 * HDIM);
}